// Round 5
// baseline (485.495 us; speedup 1.0000x reference)
//
#include <hip/hip_runtime.h>

typedef unsigned short u16;
typedef unsigned int u32;
typedef __attribute__((ext_vector_type(8))) short short8;
typedef __attribute__((ext_vector_type(4))) float f32x4;
typedef __attribute__((ext_vector_type(2))) unsigned int u32x2;
typedef __attribute__((ext_vector_type(4))) unsigned int u32x4;

__device__ __forceinline__ u16 f2bf(float f) {
  u32 u = __float_as_uint(f);
  u += 0x7FFFu + ((u >> 16) & 1u);
  return (u16)(u >> 16);
}

// Pure-polynomial exact-GELU for |x| <= 1.5 (error < 3e-6 there).
__device__ __forceinline__ float gelu_poly(float x) {
  const float v = x * x;
  float p = __builtin_fmaf(-4.12267e-8f, v, 6.65969e-7f);
  p = __builtin_fmaf(p, v, -9.44466e-6f);
  p = __builtin_fmaf(p, v, 1.15437e-4f);
  p = __builtin_fmaf(p, v, -1.1873282e-3f);
  p = __builtin_fmaf(p, v, 9.973557e-3f);
  p = __builtin_fmaf(p, v, -6.649038e-2f);
  p = __builtin_fmaf(p, v, 0.3989422804f);
  return x * __builtin_fmaf(x, p, 0.5f);
}

// Fallback for rare |x| > 1.5: A&S 7.1.26 erfc (|err|~1.5e-7), branch-free.
__device__ __forceinline__ float gelu_as(float x) {
  float ax = __builtin_fabsf(0.70710678118654752f * x);
  float t  = __builtin_amdgcn_rcpf(__builtin_fmaf(0.3275911f, ax, 1.0f));
  float p  = __builtin_fmaf(__builtin_fmaf(__builtin_fmaf(__builtin_fmaf(
               0.5307027145f, t, -0.7265760135f), t, 0.7107068705f), t,
               -0.142248368f), t, 0.127414796f);
  float e  = __expf(-(ax * ax));
  float h  = (p * t) * e;
  float phi = (x >= 0.0f) ? (1.0f - h) : h;
  return x * phi;
}

// swizzled byte offset inside a [rows][128 bf16] (256B-stride) LDS tile
__device__ __forceinline__ int swz(int row, int inrow_byte) {
  return (row * 256 + inrow_byte) ^ ((row & 7) << 4);
}

// ---- prep: weights -> bf16 transposed [n][k] in ws (PLAIN layout; B-frags
// are read directly from global now, no LDS staging, no swizzle).
// ws (u16): [0,65536): layers 1..4: L*16384 + n*128 + k (W1 k-padded 48->128)
//           [65536,67584): W5T: n*128 + k (16 cols, 4 real)
__global__ void prep_weights(const float* __restrict__ W1, const float* __restrict__ W2,
                             const float* __restrict__ W3, const float* __restrict__ W4,
                             const float* __restrict__ W5, u16* __restrict__ ws) {
  int idx = blockIdx.x * 256 + threadIdx.x;
  if (idx < 65536) {
    int L = idx >> 14, rem = idx & 16383;
    int n = rem >> 7, k = rem & 127;
    float v;
    if (L == 0)      v = (k < 48) ? W1[k * 128 + n] : 0.f;
    else if (L == 1) v = W2[k * 128 + n];
    else if (L == 2) v = W3[k * 128 + n];
    else             v = W4[k * 128 + n];
    ws[idx] = f2bf(v);
  } else if (idx < 67584) {
    int i = idx - 65536;
    int n = i >> 7, k = i & 127;
    ws[idx] = f2bf((n < 4) ? W5[k * 4 + n] : 0.f);
  }
}

// 256 threads = 4 fully-independent waves; each wave owns 32 sample-rows
// (4 queries x 8 neighbors) and a private 8KB LDS activation slab.
// ZERO __syncthreads: the only shared data (weights) is read-only global.
__global__ __launch_bounds__(256) void domino_main(
    const float* __restrict__ qp, const float* __restrict__ pts,
    const float* __restrict__ freqs,
    const float* __restrict__ b1, const float* __restrict__ b2,
    const float* __restrict__ b3, const float* __restrict__ b4,
    const float* __restrict__ b5, const int* __restrict__ mapping,
    const u16* __restrict__ wsW, float* __restrict__ out) {
  __shared__ alignas(16) u16 Abuf[4][32 * 128];   // 8KB per wave, private

  const int tid  = threadIdx.x;
  const int lane = tid & 63;
  const int wid  = tid >> 6;
  const int l15  = lane & 15;
  const int lk   = lane >> 4;
  char* const ab = (char*)(Abuf[wid]);

  const int wg   = blockIdx.x * 4 + wid;   // global wave id, 0..32767
  const int row0 = wg * 32;                // first global sample-row

  // ---- gather + fourier features (wave-private rows; packed b64 writes) ----
  {
    const int rl = lane >> 1;              // local row 0..31
    const int p  = lane & 1;               // half of the 24 scaled features
    const int rg = row0 + rl;
    const int nb = mapping[rg];
    const int mg = rg >> 3;
    float rel[3];
    #pragma unroll
    for (int d = 0; d < 3; ++d) rel[d] = pts[nb * 3 + d] - qp[mg * 3 + d];
    float sv[12], cv[12];
    #pragma unroll
    for (int t = 0; t < 12; ++t) {         // j = p*12 + t ; f = j/3 ; d = j%3
      const int f = p * 4 + t / 3;
      const int d = t % 3;
      const float a = rel[d] * freqs[f];
      sv[t] = __sinf(a);
      cv[t] = __cosf(a);
    }
    u32 sw[6], cw[6];
    #pragma unroll
    for (int i = 0; i < 6; ++i) {
      sw[i] = (u32)f2bf(sv[2 * i]) | ((u32)f2bf(sv[2 * i + 1]) << 16);
      cw[i] = (u32)f2bf(cv[2 * i]) | ((u32)f2bf(cv[2 * i + 1]) << 16);
    }
    #pragma unroll
    for (int i = 0; i < 3; ++i) {
      u32x2 s2 = {sw[2 * i], sw[2 * i + 1]};
      *(u32x2*)(ab + swz(rl, p * 24 + i * 8)) = s2;           // sin cols [0,24)
      u32x2 c2 = {cw[2 * i], cw[2 * i + 1]};
      *(u32x2*)(ab + swz(rl, 48 + p * 24 + i * 8)) = c2;      // cos cols [24,48)
    }
    u32x4 z = {0, 0, 0, 0};                                   // pad cols [48,64)
    *(u32x4*)(ab + swz(rl, 96 + p * 16)) = z;
  }
  // within-wave LDS write->read: compiler's lgkmcnt handles it; no barrier.

  const float* const BS[4] = {b1, b2, b3, b4};

  #pragma unroll
  for (int layer = 0; layer < 4; ++layer) {
    const char* Wl = (const char*)(wsW + layer * 16384);
    f32x4 acc[2][8];
    #pragma unroll
    for (int cb = 0; cb < 8; ++cb) {
      const float bv = BS[layer][cb * 16 + l15];
      f32x4 bb = {bv, bv, bv, bv};
      acc[0][cb] = bb;
      acc[1][cb] = bb;
    }
    const int KKn = (layer == 0) ? 2 : 4;   // layer0: K=48 (padded to 64)
    #pragma unroll
    for (int kk = 0; kk < 4; ++kk) {
      if (kk < KKn) {
        const short8 a0 = *(const short8*)(ab + swz(l15,      kk * 64 + lk * 16));
        const short8 a1 = *(const short8*)(ab + swz(16 + l15, kk * 64 + lk * 16));
        #pragma unroll
        for (int cb = 0; cb < 8; ++cb) {
          // B-frag straight from global (L1/L2-hot, 16 rows x 64B segments)
          const short8 bf =
              *(const short8*)(Wl + (cb * 16 + l15) * 256 + kk * 64 + lk * 16);
          acc[0][cb] = __builtin_amdgcn_mfma_f32_16x16x32_bf16(a0, bf, acc[0][cb], 0, 0, 0);
          acc[1][cb] = __builtin_amdgcn_mfma_f32_16x16x32_bf16(a1, bf, acc[1][cb], 0, 0, 0);
        }
      }
    }
    // GELU + bf16 writeback (C/D map: col=lane&15, row=(lane>>4)*4+reg).
    // All A reads for this layer are already in registers -> safe to overwrite.
    #pragma unroll
    for (int rb = 0; rb < 2; ++rb) {
      float m = 0.f;
      #pragma unroll
      for (int cb = 0; cb < 8; ++cb)
        #pragma unroll
        for (int rg = 0; rg < 4; ++rg)
          m = __builtin_fmaxf(m, __builtin_fabsf(acc[rb][cb][rg]));
      if (__any(m > 1.5f)) {               // rare wave-uniform fallback
        #pragma unroll
        for (int rg = 0; rg < 4; ++rg) {
          const int row = rb * 16 + lk * 4 + rg;
          #pragma unroll
          for (int cb = 0; cb < 8; ++cb)
            *(u16*)(ab + swz(row, (cb * 16 + l15) * 2)) = f2bf(gelu_as(acc[rb][cb][rg]));
        }
      } else {
        #pragma unroll
        for (int rg = 0; rg < 4; ++rg) {
          const int row = rb * 16 + lk * 4 + rg;
          #pragma unroll
          for (int cb = 0; cb < 8; ++cb)
            *(u16*)(ab + swz(row, (cb * 16 + l15) * 2)) = f2bf(gelu_poly(acc[rb][cb][rg]));
        }
      }
    }
  }

  // ---- layer 5: [32x128] @ W5T[16x128], then mean over 8 neighbors ----
  {
    const char* W5l = (const char*)(wsW + 65536);
    f32x4 acc5[2] = {{0.f, 0.f, 0.f, 0.f}, {0.f, 0.f, 0.f, 0.f}};
    #pragma unroll
    for (int kk = 0; kk < 4; ++kk) {
      const short8 a0 = *(const short8*)(ab + swz(l15,      kk * 64 + lk * 16));
      const short8 a1 = *(const short8*)(ab + swz(16 + l15, kk * 64 + lk * 16));
      const short8 bf = *(const short8*)(W5l + l15 * 256 + kk * 64 + lk * 16);
      acc5[0] = __builtin_amdgcn_mfma_f32_16x16x32_bf16(a0, bf, acc5[0], 0, 0, 0);
      acc5[1] = __builtin_amdgcn_mfma_f32_16x16x32_bf16(a1, bf, acc5[1], 0, 0, 0);
    }
    // D[col=l15=outfeat][row=lk*4+r=sample]. Sum 4 in-lane samples, then
    // xor-16 joins lk pairs {0,1}/{2,3} -> 8-neighbor sums per query.
    float s40 = acc5[0][0] + acc5[0][1] + acc5[0][2] + acc5[0][3];
    float s41 = acc5[1][0] + acc5[1][1] + acc5[1][2] + acc5[1][3];
    s40 += __shfl_xor(s40, 16, 64);
    s41 += __shfl_xor(s41, 16, 64);
    if ((lk & 1) == 0 && l15 < 4) {
      const int q0 = wg * 4 + (lk >> 1);   // lk=0 -> +0 ; lk=2 -> +1
      const float bv = b5[l15];
      out[(q0)     * 4 + l15] = 0.125f * s40 + bv;   // rb=0: queries 0,1
      out[(q0 + 2) * 4 + l15] = 0.125f * s41 + bv;   // rb=1: queries 2,3
    }
  }
}

extern "C" void kernel_launch(void* const* d_in, const int* in_sizes, int n_in,
                              void* d_out, int out_size, void* d_ws, size_t ws_size,
                              hipStream_t stream) {
  const float* qp      = (const float*)d_in[0];
  const float* pts     = (const float*)d_in[1];
  const float* freqs   = (const float*)d_in[2];
  const float* W1      = (const float*)d_in[3];
  const float* b1      = (const float*)d_in[4];
  const float* W2      = (const float*)d_in[5];
  const float* b2      = (const float*)d_in[6];
  const float* W3      = (const float*)d_in[7];
  const float* b3      = (const float*)d_in[8];
  const float* W4      = (const float*)d_in[9];
  const float* b4      = (const float*)d_in[10];
  const float* W5      = (const float*)d_in[11];
  const float* b5      = (const float*)d_in[12];
  const int*   mapping = (const int*)d_in[13];
  u16* ws = (u16*)d_ws;
  float* out = (float*)d_out;

  prep_weights<<<dim3(264), dim3(256), 0, stream>>>(W1, W2, W3, W4, W5, ws);
  // 32768 waves (32 rows each) / 4 waves per block = 8192 blocks
  domino_main<<<dim3(8192), dim3(256), 0, stream>>>(
      qp, pts, freqs, b1, b2, b3, b4, b5, mapping, ws, out);
}